// Round 17
// baseline (408.876 us; speedup 1.0000x reference)
//
#include <hip/hip_runtime.h>
#include <hip/hip_bf16.h>

// NCA update, round 17: R16's proven park-pipeline extended to 4 tiles
// (full row per block) + b1 folded into the MFMA via the k''=3 pad column
// (Y[3]=1.0, w1p[:,3]=b1 split hi/lo). With b1==0 this is bit-identical.

#define CCH 16
#define HID 128
#define HH 256
#define WW 256
#define BB 32

typedef __attribute__((ext_vector_type(8))) short bf16x8;
typedef __attribute__((ext_vector_type(4))) float f32x4;
typedef __attribute__((ext_vector_type(4))) int i32x4;
typedef __attribute__((ext_vector_type(2))) unsigned int u32x2;

union bfpack {
  u32x2 w2[2];
  bf16x8 v;
};

__device__ inline unsigned short f2bf(float f) {  // RNE
  unsigned int u = __float_as_uint(f);
  u += 0x7FFFu + ((u >> 16) & 1u);
  return (unsigned short)(u >> 16);
}
__device__ inline float bf2f(unsigned short s) {
  return __uint_as_float(((unsigned int)s) << 16);
}
__device__ inline unsigned int cvtpk2(float a, float b) {  // v_cvt_pk_bf16_f32
  union { __hip_bfloat162 h; unsigned int u; } cv;
  cv.h = __float22bfloat162_rn(make_float2(a, b));
  return cv.u;
}

// ---------------------------------------------------------------- prep
// w1p[(((pl*2+ks)*8 + mt)*64 + lane)*8 + j]; row = mt*16+(l&15),
// k'' = ks*32+(l>>4)*8+j; k''=c*4+f -> w1[row][c*3+f]; k''==3 -> b1[row]
// (bias column, pairs with Y[3]=1.0); other f==3 -> 0.
// w2p[((pl*4+ks)*64 + lane)*8 + j]; out-ch = l&15, k = ks*32+(l>>4)*8+j.
__global__ __launch_bounds__(256) void pack_weights_kernel(
    const float* __restrict__ w1, const float* __restrict__ b1,
    const float* __restrict__ w2, unsigned short* __restrict__ w1p,
    unsigned short* __restrict__ w2p) {
  const int tid = blockIdx.x * 256 + threadIdx.x;
  if (tid < 2048) {
    const int l = tid & 63, m = (tid >> 6) & 7, ks = (tid >> 9) & 1,
              pl = (tid >> 10) & 1;
    const int row = m * 16 + (l & 15);
    const int kb = ks * 32 + (l >> 4) * 8;
    const size_t off = ((((size_t)pl * 2 + ks) * 8 + m) * 64 + l) * 8;
#pragma unroll
    for (int j = 0; j < 8; ++j) {
      const int k = kb + j;          // k'' in [0,64)
      const int cc = k >> 2, f = k & 3;
      const float v = (f < 3) ? w1[row * 48 + cc * 3 + f]
                              : ((k == 3) ? b1[row] : 0.0f);
      const unsigned short hi = f2bf(v);
      w1p[off + j] = (pl == 0) ? hi : f2bf(v - bf2f(hi));
    }
  } else if (tid < 2560) {
    const int t2 = tid - 2048;
    const int l = t2 & 63, ks = (t2 >> 6) & 3, pl = (t2 >> 8) & 1;
    const int row = l & 15;
    const int kb = ks * 32 + (l >> 4) * 8;
    const size_t off = (((size_t)pl * 4 + ks) * 64 + l) * 8;
#pragma unroll
    for (int j = 0; j < 8; ++j) {
      const float v = w2[row * 128 + kb + j];
      const unsigned short hi = f2bf(v);
      w2p[off + j] = (pl == 0) ? hi : f2bf(v - bf2f(hi));
    }
  }
}

// Swizzle key (bytes): mixes writer-varying bits (row>>2) with reader-varying
// bits (row&3) so all Y/H access patterns are 2-way (free).
__device__ inline int swkey(int row) {
  return (((row >> 2) ^ ((row & 3) << 2)) & 15) << 3;
}

// ---------------------------------------------------------------- main
// Block = one full row (4 x 64-px tiles), 256 thr = 4 waves. Tiles T1..T4
// are independent; T2..T4's Y parked in 24 VGPRs and stored as the Y region
// frees (R16's proven schedule, iterated). 2 barriers per tile.
// LDS 24576 B: Y row px*128, H row px*256, XOR swkey.
__global__ __launch_bounds__(256, 4) void nca_mfma_kernel(
    const float* __restrict__ x, const float* __restrict__ b2,
    const unsigned short* __restrict__ w1p,
    const unsigned short* __restrict__ w2p, const int* __restrict__ fire,
    float* __restrict__ out, float* __restrict__ alpha_ws,
    unsigned char* __restrict__ pre_ws) {
  __shared__ __align__(16) unsigned char smem[24576];
  unsigned char* Ys = smem;
  unsigned char* Hsm = smem + 8192;

  const int L = blockIdx.x;
  const int orig = ((L & 7) << 10) | (L >> 3);  // XCD swizzle (8192 = 8*1024)
  const int b = orig >> 8;
  const int h = orig & 255;
  const int tid = threadIdx.x;
  const int wv = tid >> 6, lane = tid & 63, g = lane >> 4, ln = lane & 15;
  const int c = wv * 4 + g;
  const int q = ln;
  const int hm = (h + 255) & 255, hp = (h + 1) & 255;
  const float* xc = x + (size_t)(b * CCH + c) * (HH * WW);
  const float padv = (c == 0) ? 1.0f : 0.0f;  // bias column activation
  const bool edge = (q == 0 || q == 15);

  u32x2 yP[3][4];  // parked Y for T2..T4

  // FILTER(wt_): perception for one 64-px tile; Y -> LDS or park regs.
  auto FILTER = [&](int wt_, u32x2* park) {
    const int gcol0 = wt_ * 64 + q * 4;
    const f32x4 t4 = *(const f32x4*)(xc + (size_t)hm * WW + gcol0);
    const f32x4 m4 = *(const f32x4*)(xc + (size_t)h * WW + gcol0);
    const f32x4 o4 = *(const f32x4*)(xc + (size_t)hp * WW + gcol0);
    f32x4 av, bv;
#pragma unroll
    for (int j = 0; j < 4; ++j) {
      av[j] = 0.125f * (t4[j] + o4[j]) + 0.25f * m4[j];
      bv[j] = 0.125f * (o4[j] - t4[j]);
    }
    float haA = 0.f, haB = 0.f, hcm = 0.f;
    if (edge) {
      const int gc =
          (q == 15) ? ((wt_ * 64 + 64) & 255) : ((wt_ * 64 + 255) & 255);
      const float t = xc[(size_t)hm * WW + gc];
      const float m = xc[(size_t)h * WW + gc];
      const float bo = xc[(size_t)hp * WW + gc];
      haA = 0.125f * (t + bo) + 0.25f * m;
      haB = 0.125f * (bo - t);
      hcm = fmaxf(fmaxf(t, m), bo);
    }
    float aLs = __shfl(av[3], lane - 1, 64);
    float bLs = __shfl(bv[3], lane - 1, 64);
    float aRs = __shfl(av[0], lane + 1, 64);
    float bRs = __shfl(bv[0], lane + 1, 64);
    if (q == 0) { aLs = haA; bLs = haB; }
    if (q == 15) { aRs = haA; bRs = haB; }

    const int c8 = c * 8;
#pragma unroll
    for (int i = 0; i < 4; ++i) {
      const float aR = (i < 3) ? av[i + 1] : aRs;
      const float aL = (i > 0) ? av[i - 1] : aLs;
      const float bR = (i < 3) ? bv[i + 1] : bRs;
      const float bL = (i > 0) ? bv[i - 1] : bLs;
      const int px = q * 4 + i;
      u32x2 w;
      w[0] = cvtpk2(m4[i], aR - aL);
      w[1] = cvtpk2(bL + 2.0f * bv[i] + bR, padv);  // pad: 1.0 (c=0) else 0
      if (park) park[i] = w;
      else *(u32x2*)(Ys + px * 128 + (c8 ^ swkey(px))) = w;
    }
    if (c == 3) {
      f32x4 cm4;
#pragma unroll
      for (int j = 0; j < 4; ++j) cm4[j] = fmaxf(fmaxf(t4[j], m4[j]), o4[j]);
      float cmL = __shfl(cm4[3], lane - 1, 64);
      float cmR = __shfl(cm4[0], lane + 1, 64);
      if (q == 0) cmL = hcm;
      if (q == 15) cmR = hcm;
      const float p0 = fmaxf(fmaxf(cmL, cm4[0]), cm4[1]);
      const float p1 = fmaxf(fmaxf(cm4[0], cm4[1]), cm4[2]);
      const float p2 = fmaxf(fmaxf(cm4[1], cm4[2]), cm4[3]);
      const float p3 = fmaxf(fmaxf(cm4[2], cm4[3]), cmR);
      const unsigned int pb = (p0 > 0.1f ? 1u : 0u) |
                              ((p1 > 0.1f ? 1u : 0u) << 8) |
                              ((p2 > 0.1f ? 1u : 0u) << 16) |
                              ((p3 > 0.1f ? 1u : 0u) << 24);
      *(unsigned int*)(pre_ws + ((size_t)b * HH + h) * WW + gcol0) = pb;
    }
  };

  FILTER(0, nullptr);
  FILTER(1, yP[0]);
  FILTER(2, yP[1]);
  FILTER(3, yP[2]);

  // A1: loaded once for all 4 tiles (issued before barA).
  bf16x8 A1[2][4];  // [mi][hi-k0, hi-k1, lo-k0, lo-k1] for mt = 2wv+mi
#pragma unroll
  for (int mi = 0; mi < 2; ++mi)
#pragma unroll
    for (int f = 0; f < 4; ++f)
      A1[mi][f] = *(const bf16x8*)(
          w1p + (((size_t)f * 8 + (wv * 2 + mi)) * 64 + lane) * 8);

  // GEMM1: Y(LDS) -> relu -> H(LDS); bias comes free via the pad column.
  auto GEMM1 = [&]() {
#pragma unroll
    for (int ni = 0; ni < 4; ++ni) {
      const int pxb = ni * 16 + ln;
      const int sk = swkey(pxb);
      const unsigned char* rb = Ys + pxb * 128;
      bfpack B0, B1;
      B0.w2[0] = *(const u32x2*)(rb + ((g * 16) ^ sk));
      B0.w2[1] = *(const u32x2*)(rb + ((g * 16 + 8) ^ sk));
      B1.w2[0] = *(const u32x2*)(rb + ((64 + g * 16) ^ sk));
      B1.w2[1] = *(const u32x2*)(rb + ((64 + g * 16 + 8) ^ sk));
#pragma unroll
      for (int mi = 0; mi < 2; ++mi) {
        f32x4 a = (f32x4){0.f, 0.f, 0.f, 0.f};
        a = __builtin_amdgcn_mfma_f32_16x16x32_bf16(A1[mi][0], B0.v, a, 0, 0, 0);
        a = __builtin_amdgcn_mfma_f32_16x16x32_bf16(A1[mi][1], B1.v, a, 0, 0, 0);
        a = __builtin_amdgcn_mfma_f32_16x16x32_bf16(A1[mi][2], B0.v, a, 0, 0, 0);
        a = __builtin_amdgcn_mfma_f32_16x16x32_bf16(A1[mi][3], B1.v, a, 0, 0, 0);
        const int hid0 = (wv * 2 + mi) * 16 + g * 4;
        u32x2 hv;
        hv[0] = cvtpk2(fmaxf(a[0], 0.f), fmaxf(a[1], 0.f));
        hv[1] = cvtpk2(fmaxf(a[2], 0.f), fmaxf(a[3], 0.f));
        *(u32x2*)(Hsm + pxb * 256 + ((hid0 * 2) ^ sk)) = hv;
      }
    }
  };

  // GEMM2(wt_): H(LDS) -> out/alpha.
  auto GEMM2 = [&](int wt_) {
    bf16x8 A2[8];
#pragma unroll
    for (int i = 0; i < 8; ++i)
      A2[i] = *(const bf16x8*)(w2p + ((size_t)i * 64 + lane) * 8);

    const int px0 = wv * 16 + g * 4;
    const int wg0 = wt_ * 64 + px0;
    const size_t pix0 = ((size_t)b * HH + h) * WW + wg0;
    const i32x4 fi = *(const i32x4*)(fire + pix0);
    const float b2v = b2[ln];
    const size_t xi0 = (((size_t)(b * CCH + ln)) * HH + h) * WW + wg0;
    const f32x4 xo = *(const f32x4*)(x + xi0);

    const int prow = wv * 16 + ln;
    const int sk = swkey(prow);
    const unsigned char* rb = Hsm + prow * 256;
    f32x4 a = (f32x4){0.f, 0.f, 0.f, 0.f};
#pragma unroll
    for (int ks = 0; ks < 4; ++ks) {
      const int o = ks * 64 + g * 16;
      bfpack Hf;
      Hf.w2[0] = *(const u32x2*)(rb + (o ^ sk));
      Hf.w2[1] = *(const u32x2*)(rb + ((o + 8) ^ sk));
      a = __builtin_amdgcn_mfma_f32_16x16x32_bf16(Hf.v, A2[ks], a, 0, 0, 0);
      a = __builtin_amdgcn_mfma_f32_16x16x32_bf16(Hf.v, A2[4 + ks], a, 0, 0, 0);
    }
    f32x4 v;
#pragma unroll
    for (int r = 0; r < 4; ++r) v[r] = xo[r] + (a[r] + b2v) * (float)fi[r];
    *(f32x4*)(out + xi0) = v;
    if (ln == 3) *(f32x4*)(alpha_ws + pix0) = v;
  };

  // PARK(t): store parked Y for tile t+1 into the freed Y region.
  auto PARK = [&](const u32x2* yp) {
    const int c8 = c * 8;
#pragma unroll
    for (int i = 0; i < 4; ++i) {
      const int px = q * 4 + i;
      *(u32x2*)(Ys + px * 128 + (c8 ^ swkey(px))) = yp[i];
    }
  };

  __syncthreads();  // barA: Y-T1 visible
  GEMM1();
  __syncthreads();  // H-T1 visible; Y-T1 reads drained
  PARK(yP[0]);
  GEMM2(0);
  __syncthreads();  // Y-T2 visible; H-T1 reads drained
  GEMM1();
  __syncthreads();
  PARK(yP[1]);
  GEMM2(1);
  __syncthreads();
  GEMM1();
  __syncthreads();
  PARK(yP[2]);
  GEMM2(2);
  __syncthreads();
  GEMM1();
  __syncthreads();
  GEMM2(3);
}

// ---------------------------------------------------------------- life
// 4 px/thread; one wave = one full 256-px row; wrap shuffles, no halo loads.
__global__ __launch_bounds__(256) void life_mask_kernel(
    const float* __restrict__ alpha_ws, const unsigned char* __restrict__ pre_ws,
    float* __restrict__ out) {
  const int idx = blockIdx.x * 256 + threadIdx.x;  // npix/4 threads
  const int lane = idx & 63;
  const int w0 = lane * 4;
  const int h = (idx >> 6) & 255;
  const int b = idx >> 14;
  const int hm = (h + 255) & 255;
  const int hp = (h + 1) & 255;

  const float* ab = alpha_ws + (size_t)b * HH * WW;
  const f32x4 up = *(const f32x4*)(ab + (size_t)hm * WW + w0);
  const f32x4 mi = *(const f32x4*)(ab + (size_t)h * WW + w0);
  const f32x4 dn = *(const f32x4*)(ab + (size_t)hp * WW + w0);
  f32x4 cm;
#pragma unroll
  for (int j = 0; j < 4; ++j) cm[j] = fmaxf(fmaxf(up[j], mi[j]), dn[j]);

  const float cmL = __shfl(cm[3], (lane + 63) & 63, 64);  // wrap
  const float cmR = __shfl(cm[0], (lane + 1) & 63, 64);   // wrap
  const float p0 = fmaxf(fmaxf(cmL, cm[0]), cm[1]);
  const float p1 = fmaxf(fmaxf(cm[0], cm[1]), cm[2]);
  const float p2 = fmaxf(fmaxf(cm[1], cm[2]), cm[3]);
  const float p3 = fmaxf(fmaxf(cm[2], cm[3]), cmR);

  const size_t pix0 = ((size_t)b * HH + h) * WW + w0;
  const unsigned int pb = *(const unsigned int*)(pre_ws + pix0);
  const bool l0 = (p0 > 0.1f) && (pb & 0xFFu);
  const bool l1 = (p1 > 0.1f) && (pb & 0xFF00u);
  const bool l2 = (p2 > 0.1f) && (pb & 0xFF0000u);
  const bool l3 = (p3 > 0.1f) && (pb & 0xFF000000u);

  if (!(l0 && l1 && l2 && l3)) {
    const bool lv[4] = {l0, l1, l2, l3};
#pragma unroll
    for (int r = 0; r < 4; ++r) {
      if (!lv[r]) {
        float* op = out + ((size_t)b * CCH * HH + h) * WW + w0 + r;
#pragma unroll
        for (int c = 0; c < CCH; ++c) op[(size_t)c * HH * WW] = 0.0f;
      }
    }
  }
}

// ---------------------------------------------------------------- launch
extern "C" void kernel_launch(void* const* d_in, const int* in_sizes, int n_in,
                              void* d_out, int out_size, void* d_ws,
                              size_t ws_size, hipStream_t stream) {
  const float* x = (const float*)d_in[0];
  const float* w1 = (const float*)d_in[1];
  const float* b1 = (const float*)d_in[2];
  const float* w2 = (const float*)d_in[3];
  const float* b2 = (const float*)d_in[4];
  const int* fire = (const int*)d_in[5];
  float* out = (float*)d_out;

  const size_t npix = (size_t)BB * HH * WW;
  unsigned short* w1p = (unsigned short*)d_ws;
  unsigned short* w2p = (unsigned short*)((char*)d_ws + 32768);
  float* alpha_ws = (float*)((char*)d_ws + 40960);
  unsigned char* pre_ws = (unsigned char*)d_ws + 40960 + npix * sizeof(float);

  pack_weights_kernel<<<10, 256, 0, stream>>>(w1, b1, w2, w1p, w2p);
  nca_mfma_kernel<<<BB * HH, 256, 0, stream>>>(x, b2, w1p, w2p, fire, out,
                                               alpha_ws, pre_ws);
  life_mask_kernel<<<(int)(npix / 4 / 256), 256, 0, stream>>>(alpha_ws, pre_ws,
                                                              out);
}

// Round 18
// 161.581 us; speedup vs baseline: 2.5305x; 2.5305x over previous
//
#include <hip/hip_runtime.h>
#include <hip/hip_bf16.h>

// NCA update, round 18: R16 (known-good two-tile pipeline, 172.6us) + b1
// folded into the MFMA via the k''=3 pad column (Y[3]=1.0 for c==0,
// w1p[:,3]=b1 hi/lo). With b1==0 this is bit-identical to R16.

#define CCH 16
#define HID 128
#define HH 256
#define WW 256
#define BB 32

typedef __attribute__((ext_vector_type(8))) short bf16x8;
typedef __attribute__((ext_vector_type(4))) float f32x4;
typedef __attribute__((ext_vector_type(4))) int i32x4;
typedef __attribute__((ext_vector_type(2))) unsigned int u32x2;

union bfpack {
  u32x2 w2[2];
  bf16x8 v;
};

__device__ inline unsigned short f2bf(float f) {  // RNE
  unsigned int u = __float_as_uint(f);
  u += 0x7FFFu + ((u >> 16) & 1u);
  return (unsigned short)(u >> 16);
}
__device__ inline float bf2f(unsigned short s) {
  return __uint_as_float(((unsigned int)s) << 16);
}
__device__ inline unsigned int cvtpk2(float a, float b) {  // v_cvt_pk_bf16_f32
  union { __hip_bfloat162 h; unsigned int u; } cv;
  cv.h = __float22bfloat162_rn(make_float2(a, b));
  return cv.u;
}

// ---------------------------------------------------------------- prep
// w1p[(((pl*2+ks)*8 + mt)*64 + lane)*8 + j]; row = mt*16+(l&15),
// k'' = ks*32+(l>>4)*8+j; k''=c*4+f -> w1[row][c*3+f]; k''==3 -> b1[row]
// (bias column, pairs with Y[3]=1.0 at c==0); other f==3 -> 0.
// w2p[((pl*4+ks)*64 + lane)*8 + j]; out-ch = l&15, k = ks*32+(l>>4)*8+j.
__global__ __launch_bounds__(256) void pack_weights_kernel(
    const float* __restrict__ w1, const float* __restrict__ b1,
    const float* __restrict__ w2, unsigned short* __restrict__ w1p,
    unsigned short* __restrict__ w2p) {
  const int tid = blockIdx.x * 256 + threadIdx.x;
  if (tid < 2048) {
    const int l = tid & 63, m = (tid >> 6) & 7, ks = (tid >> 9) & 1,
              pl = (tid >> 10) & 1;
    const int row = m * 16 + (l & 15);
    const int kb = ks * 32 + (l >> 4) * 8;
    const size_t off = ((((size_t)pl * 2 + ks) * 8 + m) * 64 + l) * 8;
#pragma unroll
    for (int j = 0; j < 8; ++j) {
      const int k = kb + j;          // k'' in [0,64)
      const int cc = k >> 2, f = k & 3;
      const float v = (f < 3) ? w1[row * 48 + cc * 3 + f]
                              : ((k == 3) ? b1[row] : 0.0f);
      const unsigned short hi = f2bf(v);
      w1p[off + j] = (pl == 0) ? hi : f2bf(v - bf2f(hi));
    }
  } else if (tid < 2560) {
    const int t2 = tid - 2048;
    const int l = t2 & 63, ks = (t2 >> 6) & 3, pl = (t2 >> 8) & 1;
    const int row = l & 15;
    const int kb = ks * 32 + (l >> 4) * 8;
    const size_t off = (((size_t)pl * 4 + ks) * 64 + l) * 8;
#pragma unroll
    for (int j = 0; j < 8; ++j) {
      const float v = w2[row * 128 + kb + j];
      const unsigned short hi = f2bf(v);
      w2p[off + j] = (pl == 0) ? hi : f2bf(v - bf2f(hi));
    }
  }
}

// Swizzle key (bytes): mixes writer-varying bits (row>>2) with reader-varying
// bits (row&3) so all Y/H access patterns are 2-way (free).
__device__ inline int swkey(int row) {
  return (((row >> 2) ^ ((row & 3) << 2)) & 15) << 3;
}

// ---------------------------------------------------------------- main
// Block = two 64-px tiles of the same row h (wt = 2u, 2u+1), 256 thr = 4
// waves. T2's Y parked in 8 VGPRs, stored after GEMM1-T1 frees the Y
// region (R16's proven schedule). LDS 24576 B: Y row px*128, H row px*256.
__global__ __launch_bounds__(256, 4) void nca_mfma_kernel(
    const float* __restrict__ x, const float* __restrict__ b2,
    const unsigned short* __restrict__ w1p,
    const unsigned short* __restrict__ w2p, const int* __restrict__ fire,
    float* __restrict__ out, float* __restrict__ alpha_ws,
    unsigned char* __restrict__ pre_ws) {
  __shared__ __align__(16) unsigned char smem[24576];
  unsigned char* Ys = smem;
  unsigned char* Hsm = smem + 8192;

  const int L = blockIdx.x;
  const int orig = ((L & 7) << 11) | (L >> 3);  // XCD swizzle (16384 = 8*2048)
  const int b = orig >> 9;
  const int h = (orig >> 1) & 255;
  const int u = orig & 1;
  const int wt1 = u * 2, wt2 = u * 2 + 1;
  const int tid = threadIdx.x;
  const int wv = tid >> 6, lane = tid & 63, g = lane >> 4, ln = lane & 15;
  const int c = wv * 4 + g;
  const int q = ln;
  const int hm = (h + 255) & 255, hp = (h + 1) & 255;
  const float* xc = x + (size_t)(b * CCH + c) * (HH * WW);
  const float padv = (c == 0) ? 1.0f : 0.0f;  // bias-column activation

  // ================== phase A: both tiles' perception ==================
  u32x2 yP[4];  // T2's packed Y, parked until the Y region frees up

  // ---- tile T1: filter -> Y to LDS, pre-life.
  {
    const int gcol0 = wt1 * 64 + q * 4;
    const f32x4 t4 = *(const f32x4*)(xc + (size_t)hm * WW + gcol0);
    const f32x4 m4 = *(const f32x4*)(xc + (size_t)h * WW + gcol0);
    const f32x4 o4 = *(const f32x4*)(xc + (size_t)hp * WW + gcol0);
    f32x4 av, bv;
#pragma unroll
    for (int j = 0; j < 4; ++j) {
      av[j] = 0.125f * (t4[j] + o4[j]) + 0.25f * m4[j];
      bv[j] = 0.125f * (o4[j] - t4[j]);
    }
    float haA = 0.f, haB = 0.f, hcm = 0.f;
    if (q == 0 || q == 15) {
      const int gc =
          (q == 15) ? ((wt1 * 64 + 64) & 255) : ((wt1 * 64 + 255) & 255);
      const float t = xc[(size_t)hm * WW + gc];
      const float m = xc[(size_t)h * WW + gc];
      const float bo = xc[(size_t)hp * WW + gc];
      haA = 0.125f * (t + bo) + 0.25f * m;
      haB = 0.125f * (bo - t);
      hcm = fmaxf(fmaxf(t, m), bo);
    }
    float aLs = __shfl(av[3], lane - 1, 64);
    float bLs = __shfl(bv[3], lane - 1, 64);
    float aRs = __shfl(av[0], lane + 1, 64);
    float bRs = __shfl(bv[0], lane + 1, 64);
    if (q == 0) { aLs = haA; bLs = haB; }
    if (q == 15) { aRs = haA; bRs = haB; }

    const int c8 = c * 8;
#pragma unroll
    for (int i = 0; i < 4; ++i) {
      const float aR = (i < 3) ? av[i + 1] : aRs;
      const float aL = (i > 0) ? av[i - 1] : aLs;
      const float bR = (i < 3) ? bv[i + 1] : bRs;
      const float bL = (i > 0) ? bv[i - 1] : bLs;
      const int px = q * 4 + i;
      u32x2 w;
      w[0] = cvtpk2(m4[i], aR - aL);
      w[1] = cvtpk2(bL + 2.0f * bv[i] + bR, padv);
      *(u32x2*)(Ys + px * 128 + (c8 ^ swkey(px))) = w;
    }
    if (c == 3) {
      f32x4 cm4;
#pragma unroll
      for (int j = 0; j < 4; ++j) cm4[j] = fmaxf(fmaxf(t4[j], m4[j]), o4[j]);
      float cmL = __shfl(cm4[3], lane - 1, 64);
      float cmR = __shfl(cm4[0], lane + 1, 64);
      if (q == 0) cmL = hcm;
      if (q == 15) cmR = hcm;
      const float p0 = fmaxf(fmaxf(cmL, cm4[0]), cm4[1]);
      const float p1 = fmaxf(fmaxf(cm4[0], cm4[1]), cm4[2]);
      const float p2 = fmaxf(fmaxf(cm4[1], cm4[2]), cm4[3]);
      const float p3 = fmaxf(fmaxf(cm4[2], cm4[3]), cmR);
      const unsigned int pb = (p0 > 0.1f ? 1u : 0u) |
                              ((p1 > 0.1f ? 1u : 0u) << 8) |
                              ((p2 > 0.1f ? 1u : 0u) << 16) |
                              ((p3 > 0.1f ? 1u : 0u) << 24);
      *(unsigned int*)(pre_ws + ((size_t)b * HH + h) * WW + gcol0) = pb;
    }
  }

  // ---- tile T2: filter -> yP (regs), pre-life.
  {
    const int gcol0 = wt2 * 64 + q * 4;
    const f32x4 t4 = *(const f32x4*)(xc + (size_t)hm * WW + gcol0);
    const f32x4 m4 = *(const f32x4*)(xc + (size_t)h * WW + gcol0);
    const f32x4 o4 = *(const f32x4*)(xc + (size_t)hp * WW + gcol0);
    f32x4 av, bv;
#pragma unroll
    for (int j = 0; j < 4; ++j) {
      av[j] = 0.125f * (t4[j] + o4[j]) + 0.25f * m4[j];
      bv[j] = 0.125f * (o4[j] - t4[j]);
    }
    float haA = 0.f, haB = 0.f, hcm = 0.f;
    if (q == 0 || q == 15) {
      const int gc =
          (q == 15) ? ((wt2 * 64 + 64) & 255) : ((wt2 * 64 + 255) & 255);
      const float t = xc[(size_t)hm * WW + gc];
      const float m = xc[(size_t)h * WW + gc];
      const float bo = xc[(size_t)hp * WW + gc];
      haA = 0.125f * (t + bo) + 0.25f * m;
      haB = 0.125f * (bo - t);
      hcm = fmaxf(fmaxf(t, m), bo);
    }
    float aLs = __shfl(av[3], lane - 1, 64);
    float bLs = __shfl(bv[3], lane - 1, 64);
    float aRs = __shfl(av[0], lane + 1, 64);
    float bRs = __shfl(bv[0], lane + 1, 64);
    if (q == 0) { aLs = haA; bLs = haB; }
    if (q == 15) { aRs = haA; bRs = haB; }

#pragma unroll
    for (int i = 0; i < 4; ++i) {
      const float aR = (i < 3) ? av[i + 1] : aRs;
      const float aL = (i > 0) ? av[i - 1] : aLs;
      const float bR = (i < 3) ? bv[i + 1] : bRs;
      const float bL = (i > 0) ? bv[i - 1] : bLs;
      yP[i][0] = cvtpk2(m4[i], aR - aL);
      yP[i][1] = cvtpk2(bL + 2.0f * bv[i] + bR, padv);
    }
    if (c == 3) {
      f32x4 cm4;
#pragma unroll
      for (int j = 0; j < 4; ++j) cm4[j] = fmaxf(fmaxf(t4[j], m4[j]), o4[j]);
      float cmL = __shfl(cm4[3], lane - 1, 64);
      float cmR = __shfl(cm4[0], lane + 1, 64);
      if (q == 0) cmL = hcm;
      if (q == 15) cmR = hcm;
      const float p0 = fmaxf(fmaxf(cmL, cm4[0]), cm4[1]);
      const float p1 = fmaxf(fmaxf(cm4[0], cm4[1]), cm4[2]);
      const float p2 = fmaxf(fmaxf(cm4[1], cm4[2]), cm4[3]);
      const float p3 = fmaxf(fmaxf(cm4[2], cm4[3]), cmR);
      const unsigned int pb = (p0 > 0.1f ? 1u : 0u) |
                              ((p1 > 0.1f ? 1u : 0u) << 8) |
                              ((p2 > 0.1f ? 1u : 0u) << 16) |
                              ((p3 > 0.1f ? 1u : 0u) << 24);
      *(unsigned int*)(pre_ws + ((size_t)b * HH + h) * WW + gcol0) = pb;
    }
  }

  // A1: loaded once, serves both tiles (issued before barA).
  bf16x8 A1[2][4];  // [mi][hi-k0, hi-k1, lo-k0, lo-k1] for mt = 2wv+mi
#pragma unroll
  for (int mi = 0; mi < 2; ++mi)
#pragma unroll
    for (int f = 0; f < 4; ++f)
      A1[mi][f] = *(const bf16x8*)(
          w1p + (((size_t)f * 8 + (wv * 2 + mi)) * 64 + lane) * 8);

  // GEMM1: Y(LDS) -> relu -> H(LDS); bias accumulates inside the MFMA.
  auto GEMM1 = [&]() {
#pragma unroll
    for (int ni = 0; ni < 4; ++ni) {
      const int pxb = ni * 16 + ln;
      const int sk = swkey(pxb);
      const unsigned char* rb = Ys + pxb * 128;
      bfpack B0, B1;
      B0.w2[0] = *(const u32x2*)(rb + ((g * 16) ^ sk));
      B0.w2[1] = *(const u32x2*)(rb + ((g * 16 + 8) ^ sk));
      B1.w2[0] = *(const u32x2*)(rb + ((64 + g * 16) ^ sk));
      B1.w2[1] = *(const u32x2*)(rb + ((64 + g * 16 + 8) ^ sk));
#pragma unroll
      for (int mi = 0; mi < 2; ++mi) {
        f32x4 a = (f32x4){0.f, 0.f, 0.f, 0.f};
        a = __builtin_amdgcn_mfma_f32_16x16x32_bf16(A1[mi][0], B0.v, a, 0, 0, 0);
        a = __builtin_amdgcn_mfma_f32_16x16x32_bf16(A1[mi][1], B1.v, a, 0, 0, 0);
        a = __builtin_amdgcn_mfma_f32_16x16x32_bf16(A1[mi][2], B0.v, a, 0, 0, 0);
        a = __builtin_amdgcn_mfma_f32_16x16x32_bf16(A1[mi][3], B1.v, a, 0, 0, 0);
        const int hid0 = (wv * 2 + mi) * 16 + g * 4;
        u32x2 hv;
        hv[0] = cvtpk2(fmaxf(a[0], 0.f), fmaxf(a[1], 0.f));
        hv[1] = cvtpk2(fmaxf(a[2], 0.f), fmaxf(a[3], 0.f));
        *(u32x2*)(Hsm + pxb * 256 + ((hid0 * 2) ^ sk)) = hv;
      }
    }
  };

  // GEMM2(wt_): H(LDS) -> out/alpha (R16 verbatim).
  auto GEMM2 = [&](int wt_) {
    bf16x8 A2[8];
#pragma unroll
    for (int i = 0; i < 8; ++i)
      A2[i] = *(const bf16x8*)(w2p + ((size_t)i * 64 + lane) * 8);

    const int px0 = wv * 16 + g * 4;
    const int wg0 = wt_ * 64 + px0;
    const size_t pix0 = ((size_t)b * HH + h) * WW + wg0;
    const i32x4 fi = *(const i32x4*)(fire + pix0);
    const float b2v = b2[ln];
    const size_t xi0 = (((size_t)(b * CCH + ln)) * HH + h) * WW + wg0;
    const f32x4 xo = *(const f32x4*)(x + xi0);

    const int prow = wv * 16 + ln;
    const int sk = swkey(prow);
    const unsigned char* rb = Hsm + prow * 256;
    f32x4 a = (f32x4){0.f, 0.f, 0.f, 0.f};
#pragma unroll
    for (int ks = 0; ks < 4; ++ks) {
      const int o = ks * 64 + g * 16;
      bfpack Hf;
      Hf.w2[0] = *(const u32x2*)(rb + (o ^ sk));
      Hf.w2[1] = *(const u32x2*)(rb + ((o + 8) ^ sk));
      a = __builtin_amdgcn_mfma_f32_16x16x32_bf16(Hf.v, A2[ks], a, 0, 0, 0);
      a = __builtin_amdgcn_mfma_f32_16x16x32_bf16(Hf.v, A2[4 + ks], a, 0, 0, 0);
    }
    f32x4 v;
#pragma unroll
    for (int r = 0; r < 4; ++r) v[r] = xo[r] + (a[r] + b2v) * (float)fi[r];
    *(f32x4*)(out + xi0) = v;
    if (ln == 3) *(f32x4*)(alpha_ws + pix0) = v;
  };

  __syncthreads();  // barA: Y-T1 visible
  GEMM1();          // T1: Y -> H
  __syncthreads();  // barB: H-T1 visible; all Y-T1 reads drained
  {                 // park T2's Y into the freed Y region
    const int c8 = c * 8;
#pragma unroll
    for (int i = 0; i < 4; ++i) {
      const int px = q * 4 + i;
      *(u32x2*)(Ys + px * 128 + (c8 ^ swkey(px))) = yP[i];
    }
  }
  GEMM2(wt1);       // T1 epilogue (overlaps the park stores)
  __syncthreads();  // barC: Y-T2 visible; all H-T1 reads drained
  GEMM1();          // T2
  __syncthreads();  // barD: H-T2 visible
  GEMM2(wt2);       // T2 epilogue
}

// ---------------------------------------------------------------- life
// 4 px/thread; one wave = one full 256-px row; wrap shuffles, no halo loads.
__global__ __launch_bounds__(256) void life_mask_kernel(
    const float* __restrict__ alpha_ws, const unsigned char* __restrict__ pre_ws,
    float* __restrict__ out) {
  const int idx = blockIdx.x * 256 + threadIdx.x;  // npix/4 threads
  const int lane = idx & 63;
  const int w0 = lane * 4;
  const int h = (idx >> 6) & 255;
  const int b = idx >> 14;
  const int hm = (h + 255) & 255;
  const int hp = (h + 1) & 255;

  const float* ab = alpha_ws + (size_t)b * HH * WW;
  const f32x4 up = *(const f32x4*)(ab + (size_t)hm * WW + w0);
  const f32x4 mi = *(const f32x4*)(ab + (size_t)h * WW + w0);
  const f32x4 dn = *(const f32x4*)(ab + (size_t)hp * WW + w0);
  f32x4 cm;
#pragma unroll
  for (int j = 0; j < 4; ++j) cm[j] = fmaxf(fmaxf(up[j], mi[j]), dn[j]);

  const float cmL = __shfl(cm[3], (lane + 63) & 63, 64);  // wrap
  const float cmR = __shfl(cm[0], (lane + 1) & 63, 64);   // wrap
  const float p0 = fmaxf(fmaxf(cmL, cm[0]), cm[1]);
  const float p1 = fmaxf(fmaxf(cm[0], cm[1]), cm[2]);
  const float p2 = fmaxf(fmaxf(cm[1], cm[2]), cm[3]);
  const float p3 = fmaxf(fmaxf(cm[2], cm[3]), cmR);

  const size_t pix0 = ((size_t)b * HH + h) * WW + w0;
  const unsigned int pb = *(const unsigned int*)(pre_ws + pix0);
  const bool l0 = (p0 > 0.1f) && (pb & 0xFFu);
  const bool l1 = (p1 > 0.1f) && (pb & 0xFF00u);
  const bool l2 = (p2 > 0.1f) && (pb & 0xFF0000u);
  const bool l3 = (p3 > 0.1f) && (pb & 0xFF000000u);

  if (!(l0 && l1 && l2 && l3)) {
    const bool lv[4] = {l0, l1, l2, l3};
#pragma unroll
    for (int r = 0; r < 4; ++r) {
      if (!lv[r]) {
        float* op = out + ((size_t)b * CCH * HH + h) * WW + w0 + r;
#pragma unroll
        for (int c = 0; c < CCH; ++c) op[(size_t)c * HH * WW] = 0.0f;
      }
    }
  }
}

// ---------------------------------------------------------------- launch
extern "C" void kernel_launch(void* const* d_in, const int* in_sizes, int n_in,
                              void* d_out, int out_size, void* d_ws,
                              size_t ws_size, hipStream_t stream) {
  const float* x = (const float*)d_in[0];
  const float* w1 = (const float*)d_in[1];
  const float* b1 = (const float*)d_in[2];
  const float* w2 = (const float*)d_in[3];
  const float* b2 = (const float*)d_in[4];
  const int* fire = (const int*)d_in[5];
  float* out = (float*)d_out;

  const size_t npix = (size_t)BB * HH * WW;
  unsigned short* w1p = (unsigned short*)d_ws;
  unsigned short* w2p = (unsigned short*)((char*)d_ws + 32768);
  float* alpha_ws = (float*)((char*)d_ws + 40960);
  unsigned char* pre_ws = (unsigned char*)d_ws + 40960 + npix * sizeof(float);

  pack_weights_kernel<<<10, 256, 0, stream>>>(w1, b1, w2, w1p, w2p);
  nca_mfma_kernel<<<BB * HH * 2, 256, 0, stream>>>(x, b2, w1p, w2p, fire, out,
                                                   alpha_ws, pre_ws);
  life_mask_kernel<<<(int)(npix / 4 / 256), 256, 0, stream>>>(alpha_ws, pre_ws,
                                                              out);
}

// Round 19
// 141.008 us; speedup vs baseline: 2.8997x; 1.1459x over previous
//
#include <hip/hip_runtime.h>
#include <hip/hip_bf16.h>

// NCA update, round 19: R18 (two-tile pipeline + b1-fold, 161.6us) with the
// weight lo-planes dropped: plain-bf16 W1/W2 (hi only). Error budget:
// Y-bf16 and H-bf16 dominate (already present); weight-rounding adds ~1e-3,
// total ~3-4e-3 < the 7.8e-3 bf16 comparison floor. Halves MFMA count.

#define CCH 16
#define HID 128
#define HH 256
#define WW 256
#define BB 32

typedef __attribute__((ext_vector_type(8))) short bf16x8;
typedef __attribute__((ext_vector_type(4))) float f32x4;
typedef __attribute__((ext_vector_type(4))) int i32x4;
typedef __attribute__((ext_vector_type(2))) unsigned int u32x2;

union bfpack {
  u32x2 w2[2];
  bf16x8 v;
};

__device__ inline unsigned short f2bf(float f) {  // RNE
  unsigned int u = __float_as_uint(f);
  u += 0x7FFFu + ((u >> 16) & 1u);
  return (unsigned short)(u >> 16);
}
__device__ inline unsigned int cvtpk2(float a, float b) {  // v_cvt_pk_bf16_f32
  union { __hip_bfloat162 h; unsigned int u; } cv;
  cv.h = __float22bfloat162_rn(make_float2(a, b));
  return cv.u;
}

// ---------------------------------------------------------------- prep
// w1p[((ks*8 + mt)*64 + lane)*8 + j]; row = mt*16+(l&15),
// k'' = ks*32+(l>>4)*8+j; k''=c*4+f -> w1[row][c*3+f]; k''==3 -> b1[row]
// (bias column, pairs with Y[3]=1.0 at c==0); other f==3 -> 0. bf16 (hi only).
// w2p[(ks*64 + lane)*8 + j]; out-ch = l&15, k = ks*32+(l>>4)*8+j. bf16.
__global__ __launch_bounds__(256) void pack_weights_kernel(
    const float* __restrict__ w1, const float* __restrict__ b1,
    const float* __restrict__ w2, unsigned short* __restrict__ w1p,
    unsigned short* __restrict__ w2p) {
  const int tid = blockIdx.x * 256 + threadIdx.x;
  if (tid < 1024) {
    const int l = tid & 63, m = (tid >> 6) & 7, ks = (tid >> 9) & 1;
    const int row = m * 16 + (l & 15);
    const int kb = ks * 32 + (l >> 4) * 8;
    const size_t off = (((size_t)ks * 8 + m) * 64 + l) * 8;
#pragma unroll
    for (int j = 0; j < 8; ++j) {
      const int k = kb + j;          // k'' in [0,64)
      const int cc = k >> 2, f = k & 3;
      const float v = (f < 3) ? w1[row * 48 + cc * 3 + f]
                              : ((k == 3) ? b1[row] : 0.0f);
      w1p[off + j] = f2bf(v);
    }
  } else if (tid < 1280) {
    const int t2 = tid - 1024;
    const int l = t2 & 63, ks = (t2 >> 6) & 3;
    const int row = l & 15;
    const int kb = ks * 32 + (l >> 4) * 8;
    const size_t off = ((size_t)ks * 64 + l) * 8;
#pragma unroll
    for (int j = 0; j < 8; ++j) w2p[off + j] = f2bf(w2[row * 128 + kb + j]);
  }
}

// Swizzle key (bytes): mixes writer-varying bits (row>>2) with reader-varying
// bits (row&3) so all Y/H access patterns are 2-way (free).
__device__ inline int swkey(int row) {
  return (((row >> 2) ^ ((row & 3) << 2)) & 15) << 3;
}

// ---------------------------------------------------------------- main
// Block = two 64-px tiles of the same row h (wt = 2u, 2u+1), 256 thr = 4
// waves. T2's Y parked in 8 VGPRs, stored after GEMM1-T1 frees the Y
// region (R16's proven schedule). LDS 24576 B: Y row px*128, H row px*256.
__global__ __launch_bounds__(256, 4) void nca_mfma_kernel(
    const float* __restrict__ x, const float* __restrict__ b2,
    const unsigned short* __restrict__ w1p,
    const unsigned short* __restrict__ w2p, const int* __restrict__ fire,
    float* __restrict__ out, float* __restrict__ alpha_ws,
    unsigned char* __restrict__ pre_ws) {
  __shared__ __align__(16) unsigned char smem[24576];
  unsigned char* Ys = smem;
  unsigned char* Hsm = smem + 8192;

  const int L = blockIdx.x;
  const int orig = ((L & 7) << 11) | (L >> 3);  // XCD swizzle (16384 = 8*2048)
  const int b = orig >> 9;
  const int h = (orig >> 1) & 255;
  const int u = orig & 1;
  const int wt1 = u * 2, wt2 = u * 2 + 1;
  const int tid = threadIdx.x;
  const int wv = tid >> 6, lane = tid & 63, g = lane >> 4, ln = lane & 15;
  const int c = wv * 4 + g;
  const int q = ln;
  const int hm = (h + 255) & 255, hp = (h + 1) & 255;
  const float* xc = x + (size_t)(b * CCH + c) * (HH * WW);
  const float padv = (c == 0) ? 1.0f : 0.0f;  // bias-column activation

  // ================== phase A: both tiles' perception ==================
  u32x2 yP[4];  // T2's packed Y, parked until the Y region frees up

  // ---- tile T1: filter -> Y to LDS, pre-life.
  {
    const int gcol0 = wt1 * 64 + q * 4;
    const f32x4 t4 = *(const f32x4*)(xc + (size_t)hm * WW + gcol0);
    const f32x4 m4 = *(const f32x4*)(xc + (size_t)h * WW + gcol0);
    const f32x4 o4 = *(const f32x4*)(xc + (size_t)hp * WW + gcol0);
    f32x4 av, bv;
#pragma unroll
    for (int j = 0; j < 4; ++j) {
      av[j] = 0.125f * (t4[j] + o4[j]) + 0.25f * m4[j];
      bv[j] = 0.125f * (o4[j] - t4[j]);
    }
    float haA = 0.f, haB = 0.f, hcm = 0.f;
    if (q == 0 || q == 15) {
      const int gc =
          (q == 15) ? ((wt1 * 64 + 64) & 255) : ((wt1 * 64 + 255) & 255);
      const float t = xc[(size_t)hm * WW + gc];
      const float m = xc[(size_t)h * WW + gc];
      const float bo = xc[(size_t)hp * WW + gc];
      haA = 0.125f * (t + bo) + 0.25f * m;
      haB = 0.125f * (bo - t);
      hcm = fmaxf(fmaxf(t, m), bo);
    }
    float aLs = __shfl(av[3], lane - 1, 64);
    float bLs = __shfl(bv[3], lane - 1, 64);
    float aRs = __shfl(av[0], lane + 1, 64);
    float bRs = __shfl(bv[0], lane + 1, 64);
    if (q == 0) { aLs = haA; bLs = haB; }
    if (q == 15) { aRs = haA; bRs = haB; }

    const int c8 = c * 8;
#pragma unroll
    for (int i = 0; i < 4; ++i) {
      const float aR = (i < 3) ? av[i + 1] : aRs;
      const float aL = (i > 0) ? av[i - 1] : aLs;
      const float bR = (i < 3) ? bv[i + 1] : bRs;
      const float bL = (i > 0) ? bv[i - 1] : bLs;
      const int px = q * 4 + i;
      u32x2 w;
      w[0] = cvtpk2(m4[i], aR - aL);
      w[1] = cvtpk2(bL + 2.0f * bv[i] + bR, padv);
      *(u32x2*)(Ys + px * 128 + (c8 ^ swkey(px))) = w;
    }
    if (c == 3) {
      f32x4 cm4;
#pragma unroll
      for (int j = 0; j < 4; ++j) cm4[j] = fmaxf(fmaxf(t4[j], m4[j]), o4[j]);
      float cmL = __shfl(cm4[3], lane - 1, 64);
      float cmR = __shfl(cm4[0], lane + 1, 64);
      if (q == 0) cmL = hcm;
      if (q == 15) cmR = hcm;
      const float p0 = fmaxf(fmaxf(cmL, cm4[0]), cm4[1]);
      const float p1 = fmaxf(fmaxf(cm4[0], cm4[1]), cm4[2]);
      const float p2 = fmaxf(fmaxf(cm4[1], cm4[2]), cm4[3]);
      const float p3 = fmaxf(fmaxf(cm4[2], cm4[3]), cmR);
      const unsigned int pb = (p0 > 0.1f ? 1u : 0u) |
                              ((p1 > 0.1f ? 1u : 0u) << 8) |
                              ((p2 > 0.1f ? 1u : 0u) << 16) |
                              ((p3 > 0.1f ? 1u : 0u) << 24);
      *(unsigned int*)(pre_ws + ((size_t)b * HH + h) * WW + gcol0) = pb;
    }
  }

  // ---- tile T2: filter -> yP (regs), pre-life.
  {
    const int gcol0 = wt2 * 64 + q * 4;
    const f32x4 t4 = *(const f32x4*)(xc + (size_t)hm * WW + gcol0);
    const f32x4 m4 = *(const f32x4*)(xc + (size_t)h * WW + gcol0);
    const f32x4 o4 = *(const f32x4*)(xc + (size_t)hp * WW + gcol0);
    f32x4 av, bv;
#pragma unroll
    for (int j = 0; j < 4; ++j) {
      av[j] = 0.125f * (t4[j] + o4[j]) + 0.25f * m4[j];
      bv[j] = 0.125f * (o4[j] - t4[j]);
    }
    float haA = 0.f, haB = 0.f, hcm = 0.f;
    if (q == 0 || q == 15) {
      const int gc =
          (q == 15) ? ((wt2 * 64 + 64) & 255) : ((wt2 * 64 + 255) & 255);
      const float t = xc[(size_t)hm * WW + gc];
      const float m = xc[(size_t)h * WW + gc];
      const float bo = xc[(size_t)hp * WW + gc];
      haA = 0.125f * (t + bo) + 0.25f * m;
      haB = 0.125f * (bo - t);
      hcm = fmaxf(fmaxf(t, m), bo);
    }
    float aLs = __shfl(av[3], lane - 1, 64);
    float bLs = __shfl(bv[3], lane - 1, 64);
    float aRs = __shfl(av[0], lane + 1, 64);
    float bRs = __shfl(bv[0], lane + 1, 64);
    if (q == 0) { aLs = haA; bLs = haB; }
    if (q == 15) { aRs = haA; bRs = haB; }

#pragma unroll
    for (int i = 0; i < 4; ++i) {
      const float aR = (i < 3) ? av[i + 1] : aRs;
      const float aL = (i > 0) ? av[i - 1] : aLs;
      const float bR = (i < 3) ? bv[i + 1] : bRs;
      const float bL = (i > 0) ? bv[i - 1] : bLs;
      yP[i][0] = cvtpk2(m4[i], aR - aL);
      yP[i][1] = cvtpk2(bL + 2.0f * bv[i] + bR, padv);
    }
    if (c == 3) {
      f32x4 cm4;
#pragma unroll
      for (int j = 0; j < 4; ++j) cm4[j] = fmaxf(fmaxf(t4[j], m4[j]), o4[j]);
      float cmL = __shfl(cm4[3], lane - 1, 64);
      float cmR = __shfl(cm4[0], lane + 1, 64);
      if (q == 0) cmL = hcm;
      if (q == 15) cmR = hcm;
      const float p0 = fmaxf(fmaxf(cmL, cm4[0]), cm4[1]);
      const float p1 = fmaxf(fmaxf(cm4[0], cm4[1]), cm4[2]);
      const float p2 = fmaxf(fmaxf(cm4[1], cm4[2]), cm4[3]);
      const float p3 = fmaxf(fmaxf(cm4[2], cm4[3]), cmR);
      const unsigned int pb = (p0 > 0.1f ? 1u : 0u) |
                              ((p1 > 0.1f ? 1u : 0u) << 8) |
                              ((p2 > 0.1f ? 1u : 0u) << 16) |
                              ((p3 > 0.1f ? 1u : 0u) << 24);
      *(unsigned int*)(pre_ws + ((size_t)b * HH + h) * WW + gcol0) = pb;
    }
  }

  // A1 (bf16 W1, hi only): loaded once, serves both tiles.
  bf16x8 A1[2][2];  // [mi][ks] for mt = 2wv+mi
#pragma unroll
  for (int mi = 0; mi < 2; ++mi)
#pragma unroll
    for (int ks = 0; ks < 2; ++ks)
      A1[mi][ks] = *(const bf16x8*)(
          w1p + (((size_t)ks * 8 + (wv * 2 + mi)) * 64 + lane) * 8);

  // GEMM1: Y(LDS) -> relu -> H(LDS); bias accumulates inside the MFMA.
  auto GEMM1 = [&]() {
#pragma unroll
    for (int ni = 0; ni < 4; ++ni) {
      const int pxb = ni * 16 + ln;
      const int sk = swkey(pxb);
      const unsigned char* rb = Ys + pxb * 128;
      bfpack B0, B1;
      B0.w2[0] = *(const u32x2*)(rb + ((g * 16) ^ sk));
      B0.w2[1] = *(const u32x2*)(rb + ((g * 16 + 8) ^ sk));
      B1.w2[0] = *(const u32x2*)(rb + ((64 + g * 16) ^ sk));
      B1.w2[1] = *(const u32x2*)(rb + ((64 + g * 16 + 8) ^ sk));
#pragma unroll
      for (int mi = 0; mi < 2; ++mi) {
        f32x4 a = (f32x4){0.f, 0.f, 0.f, 0.f};
        a = __builtin_amdgcn_mfma_f32_16x16x32_bf16(A1[mi][0], B0.v, a, 0, 0, 0);
        a = __builtin_amdgcn_mfma_f32_16x16x32_bf16(A1[mi][1], B1.v, a, 0, 0, 0);
        const int hid0 = (wv * 2 + mi) * 16 + g * 4;
        u32x2 hv;
        hv[0] = cvtpk2(fmaxf(a[0], 0.f), fmaxf(a[1], 0.f));
        hv[1] = cvtpk2(fmaxf(a[2], 0.f), fmaxf(a[3], 0.f));
        *(u32x2*)(Hsm + pxb * 256 + ((hid0 * 2) ^ sk)) = hv;
      }
    }
  };

  // GEMM2(wt_): H(LDS) -> out/alpha; W2 bf16 (hi only).
  auto GEMM2 = [&](int wt_) {
    bf16x8 A2[4];
#pragma unroll
    for (int i = 0; i < 4; ++i)
      A2[i] = *(const bf16x8*)(w2p + ((size_t)i * 64 + lane) * 8);

    const int px0 = wv * 16 + g * 4;
    const int wg0 = wt_ * 64 + px0;
    const size_t pix0 = ((size_t)b * HH + h) * WW + wg0;
    const i32x4 fi = *(const i32x4*)(fire + pix0);
    const float b2v = b2[ln];
    const size_t xi0 = (((size_t)(b * CCH + ln)) * HH + h) * WW + wg0;
    const f32x4 xo = *(const f32x4*)(x + xi0);

    const int prow = wv * 16 + ln;
    const int sk = swkey(prow);
    const unsigned char* rb = Hsm + prow * 256;
    f32x4 a = (f32x4){0.f, 0.f, 0.f, 0.f};
#pragma unroll
    for (int ks = 0; ks < 4; ++ks) {
      const int o = ks * 64 + g * 16;
      bfpack Hf;
      Hf.w2[0] = *(const u32x2*)(rb + (o ^ sk));
      Hf.w2[1] = *(const u32x2*)(rb + ((o + 8) ^ sk));
      a = __builtin_amdgcn_mfma_f32_16x16x32_bf16(Hf.v, A2[ks], a, 0, 0, 0);
    }
    f32x4 v;
#pragma unroll
    for (int r = 0; r < 4; ++r) v[r] = xo[r] + (a[r] + b2v) * (float)fi[r];
    *(f32x4*)(out + xi0) = v;
    if (ln == 3) *(f32x4*)(alpha_ws + pix0) = v;
  };

  __syncthreads();  // barA: Y-T1 visible
  GEMM1();          // T1: Y -> H
  __syncthreads();  // barB: H-T1 visible; all Y-T1 reads drained
  {                 // park T2's Y into the freed Y region
    const int c8 = c * 8;
#pragma unroll
    for (int i = 0; i < 4; ++i) {
      const int px = q * 4 + i;
      *(u32x2*)(Ys + px * 128 + (c8 ^ swkey(px))) = yP[i];
    }
  }
  GEMM2(wt1);       // T1 epilogue (overlaps the park stores)
  __syncthreads();  // barC: Y-T2 visible; all H-T1 reads drained
  GEMM1();          // T2
  __syncthreads();  // barD: H-T2 visible
  GEMM2(wt2);       // T2 epilogue
}

// ---------------------------------------------------------------- life
// 4 px/thread; one wave = one full 256-px row; wrap shuffles, no halo loads.
__global__ __launch_bounds__(256) void life_mask_kernel(
    const float* __restrict__ alpha_ws, const unsigned char* __restrict__ pre_ws,
    float* __restrict__ out) {
  const int idx = blockIdx.x * 256 + threadIdx.x;  // npix/4 threads
  const int lane = idx & 63;
  const int w0 = lane * 4;
  const int h = (idx >> 6) & 255;
  const int b = idx >> 14;
  const int hm = (h + 255) & 255;
  const int hp = (h + 1) & 255;

  const float* ab = alpha_ws + (size_t)b * HH * WW;
  const f32x4 up = *(const f32x4*)(ab + (size_t)hm * WW + w0);
  const f32x4 mi = *(const f32x4*)(ab + (size_t)h * WW + w0);
  const f32x4 dn = *(const f32x4*)(ab + (size_t)hp * WW + w0);
  f32x4 cm;
#pragma unroll
  for (int j = 0; j < 4; ++j) cm[j] = fmaxf(fmaxf(up[j], mi[j]), dn[j]);

  const float cmL = __shfl(cm[3], (lane + 63) & 63, 64);  // wrap
  const float cmR = __shfl(cm[0], (lane + 1) & 63, 64);   // wrap
  const float p0 = fmaxf(fmaxf(cmL, cm[0]), cm[1]);
  const float p1 = fmaxf(fmaxf(cm[0], cm[1]), cm[2]);
  const float p2 = fmaxf(fmaxf(cm[1], cm[2]), cm[3]);
  const float p3 = fmaxf(fmaxf(cm[2], cm[3]), cmR);

  const size_t pix0 = ((size_t)b * HH + h) * WW + w0;
  const unsigned int pb = *(const unsigned int*)(pre_ws + pix0);
  const bool l0 = (p0 > 0.1f) && (pb & 0xFFu);
  const bool l1 = (p1 > 0.1f) && (pb & 0xFF00u);
  const bool l2 = (p2 > 0.1f) && (pb & 0xFF0000u);
  const bool l3 = (p3 > 0.1f) && (pb & 0xFF000000u);

  if (!(l0 && l1 && l2 && l3)) {
    const bool lv[4] = {l0, l1, l2, l3};
#pragma unroll
    for (int r = 0; r < 4; ++r) {
      if (!lv[r]) {
        float* op = out + ((size_t)b * CCH * HH + h) * WW + w0 + r;
#pragma unroll
        for (int c = 0; c < CCH; ++c) op[(size_t)c * HH * WW] = 0.0f;
      }
    }
  }
}

// ---------------------------------------------------------------- launch
extern "C" void kernel_launch(void* const* d_in, const int* in_sizes, int n_in,
                              void* d_out, int out_size, void* d_ws,
                              size_t ws_size, hipStream_t stream) {
  const float* x = (const float*)d_in[0];
  const float* w1 = (const float*)d_in[1];
  const float* b1 = (const float*)d_in[2];
  const float* w2 = (const float*)d_in[3];
  const float* b2 = (const float*)d_in[4];
  const int* fire = (const int*)d_in[5];
  float* out = (float*)d_out;

  const size_t npix = (size_t)BB * HH * WW;
  unsigned short* w1p = (unsigned short*)d_ws;                     // 16 KB
  unsigned short* w2p = (unsigned short*)((char*)d_ws + 16384);    // 4 KB
  float* alpha_ws = (float*)((char*)d_ws + 40960);
  unsigned char* pre_ws = (unsigned char*)d_ws + 40960 + npix * sizeof(float);

  pack_weights_kernel<<<5, 256, 0, stream>>>(w1, b1, w2, w1p, w2p);
  nca_mfma_kernel<<<BB * HH * 2, 256, 0, stream>>>(x, b2, w1p, w2p, fire, out,
                                                   alpha_ws, pre_ws);
  life_mask_kernel<<<(int)(npix / 4 / 256), 256, 0, stream>>>(alpha_ws, pre_ws,
                                                              out);
}